// Round 6
// baseline (1487.956 us; speedup 1.0000x reference)
//
#include <hip/hip_runtime.h>
#include <math.h>

#define N_PIX (512*512)
#define NB 156
#define GH 64

typedef unsigned short u16;
typedef __attribute__((ext_vector_type(8))) short bfrag8;   // 8 bf16 = 4 VGPRs
typedef __attribute__((ext_vector_type(4))) float f32x4;    // MFMA accumulator

// ---------- bf16 split helpers (RNE) ----------
__device__ __forceinline__ u16 f2bf(float x){
  unsigned u = __float_as_uint(x);
  unsigned r = (u + 0x7FFFu + ((u >> 16) & 1u)) >> 16;
  return (u16)r;
}
__device__ __forceinline__ float bf2f(u16 h){
  return __uint_as_float(((unsigned)h) << 16);
}

__device__ __forceinline__ float waveReduceMax(float v){
  #pragma unroll
  for(int o=32;o>0;o>>=1) v = fmaxf(v, __shfl_down(v, o, 64));
  return v;
}
__device__ __forceinline__ float waveReduceSum(float v){
  #pragma unroll
  for(int o=32;o>0;o>>=1) v += __shfl_down(v, o, 64);
  return v;
}

// ---------- derived constants: softmax(scale_weights), clip(alpha) ----------
__global__ void k_prep(const float* __restrict__ sw, const float* __restrict__ alpha, float* __restrict__ cst){
  if(threadIdx.x==0 && blockIdx.x==0){
    float m = fmaxf(sw[0], fmaxf(sw[1], sw[2]));
    float e0=expf(sw[0]-m), e1=expf(sw[1]-m), e2=expf(sw[2]-m);
    float s = e0+e1+e2;
    cst[0]=e0/s; cst[1]=e1/s; cst[2]=e2/s;
    cst[3]=fminf(fmaxf(alpha[0],0.f),1.f);
  }
}

// ---------- CSR build ----------
__global__ void k_count(const int* __restrict__ s0, const int* __restrict__ s1, const int* __restrict__ s2,
                        int* c0, int* c1, int* c2){
  int p = blockIdx.x*256 + threadIdx.x;
  if(p < N_PIX){
    atomicAdd(&c0[s0[p]],1);
    atomicAdd(&c1[s1[p]],1);
    atomicAdd(&c2[s2[p]],1);
  }
}

__global__ __launch_bounds__(256) void k_scan(const int* __restrict__ c0, const int* __restrict__ c1, const int* __restrict__ c2,
                       int* o0, int* o1, int* o2, int* u0, int* u1, int* u2){
  const int* cnt; int* offs; int* cur; int n;
  if(blockIdx.x==0){ cnt=c0; offs=o0; cur=u0; n=2000; }
  else if(blockIdx.x==1){ cnt=c1; offs=o1; cur=u1; n=1000; }
  else { cnt=c2; offs=o2; cur=u2; n=500; }
  __shared__ int l[2048];
  __shared__ int cs[256];
  int t = threadIdx.x;
  for(int i=t;i<2048;i+=256) l[i] = (i<n) ? cnt[i] : 0;
  __syncthreads();
  int s = 0;
  #pragma unroll
  for(int j=0;j<8;j++) s += l[t*8+j];
  cs[t] = s;
  __syncthreads();
  for(int d=1; d<256; d<<=1){
    int v = (t>=d) ? cs[t-d] : 0;
    __syncthreads();
    cs[t] += v;
    __syncthreads();
  }
  int run = cs[t] - s;
  for(int j=0;j<8;j++){
    int idx = t*8+j;
    int o = run;
    run += l[idx];
    if(idx < n){ offs[idx] = o; cur[idx] = o; }
  }
}

__global__ void k_fill(const int* __restrict__ s0, const int* __restrict__ s1, const int* __restrict__ s2,
                       int* u0, int* u1, int* u2, int* L0, int* L1, int* L2){
  int p = blockIdx.x*256 + threadIdx.x;
  if(p < N_PIX){
    int a = atomicAdd(&u0[s0[p]],1); L0[a] = p;
    int b = atomicAdd(&u1[s1[p]],1); L1[b] = p;
    int c = atomicAdd(&u2[s2[p]],1); L2[c] = p;
  }
}

// ---------- fused segment mean over all 3 scales: block per segment, float2 over bands ----------
__global__ __launch_bounds__(128) void k_segmean3(const float* __restrict__ Y,
    const int* __restrict__ o0, const int* __restrict__ c0, const int* __restrict__ l0, float* __restrict__ X0,
    const int* __restrict__ o1, const int* __restrict__ c1, const int* __restrict__ l1, float* __restrict__ X1,
    const int* __restrict__ o2, const int* __restrict__ c2, const int* __restrict__ l2, float* __restrict__ X2){
  int b = blockIdx.x;
  const int *offs, *cnt, *list; float* X; int s;
  if(b < 2000){ s=b;      offs=o0; cnt=c0; list=l0; X=X0; }
  else if(b < 3000){ s=b-2000; offs=o1; cnt=c1; list=l1; X=X1; }
  else { s=b-3000; offs=o2; cnt=c2; list=l2; X=X2; }
  int t = threadIdx.x;
  int n = cnt[s], st = offs[s];
  if(t < 78){
    float ax=0.f, ay=0.f;
    int q = 0;
    for(; q+4<=n; q+=4){
      int p0 = list[st+q], p1 = list[st+q+1], p2 = list[st+q+2], p3 = list[st+q+3];
      float2 v0 = *(const float2*)(Y + (size_t)p0*NB + t*2);
      float2 v1 = *(const float2*)(Y + (size_t)p1*NB + t*2);
      float2 v2 = *(const float2*)(Y + (size_t)p2*NB + t*2);
      float2 v3 = *(const float2*)(Y + (size_t)p3*NB + t*2);
      ax += (v0.x + v1.x) + (v2.x + v3.x);
      ay += (v0.y + v1.y) + (v2.y + v3.y);
    }
    for(; q<n; q++){
      int p0 = list[st+q];
      float2 v0 = *(const float2*)(Y + (size_t)p0*NB + t*2);
      ax += v0.x; ay += v0.y;
    }
    float inv = 1.f / fmaxf((float)n, 1.f);
    float2 r; r.x = ax*inv; r.y = ay*inv;
    *(float2*)(X + (size_t)s*NB + t*2) = r;
  }
}

// ---------- generic small linear: out[n,D] = X[n,K]@W[K,D]+b ----------
__global__ void k_linear(const float* __restrict__ X, const float* __restrict__ W, const float* __restrict__ bias,
                         float* __restrict__ out, int n, int K, int D){
  int gid = blockIdx.x*256 + threadIdx.x;
  if(gid >= n*D) return;
  int r = gid / D, c = gid - r*D;
  const float* xr = X + (size_t)r*K;
  float acc = bias[c];
  for(int k=0;k<K;k++) acc = fmaf(xr[k], W[(size_t)k*D + c], acc);
  out[gid] = acc;
}

// ---------- GAT masked attention, 4 rows per block ----------
template<int D, bool FINAL>
__global__ __launch_bounds__(256) void k_attn4(const float* __restrict__ Hn, const int* __restrict__ A,
                                               float* __restrict__ out, int n){
  __shared__ float sc[4][2048];
  __shared__ float hr[4][GH];
  __shared__ float redm[4][4];
  __shared__ float outp[4][4][GH];   // part, r, c (D==64)
  __shared__ float out3[4][4][4];    // wave, r, c (D==3)
  const int t = threadIdx.x, w = t>>6, lane = t&63;
  const int r0 = blockIdx.x*4;
  if(D==GH){
    hr[w][lane] = Hn[(size_t)(r0 + w)*GH + lane];
  } else {
    if(t < 12) hr[t/3][t%3] = Hn[(size_t)(r0 + t/3)*3 + (t%3)];
  }
  __syncthreads();
  float lm0=-INFINITY, lm1=-INFINITY, lm2=-INFINITY, lm3=-INFINITY;
  for(int j=t; j<n; j+=256){
    float s0,s1,s2,s3;
    if(D==GH){
      const float4* hj = (const float4*)(Hn + (size_t)j*GH);
      s0=s1=s2=s3=0.f;
      #pragma unroll
      for(int k4=0;k4<GH/4;k4++){
        float4 h  = hj[k4];
        float4 a0 = *(const float4*)&hr[0][k4*4];
        float4 a1 = *(const float4*)&hr[1][k4*4];
        float4 a2 = *(const float4*)&hr[2][k4*4];
        float4 a3 = *(const float4*)&hr[3][k4*4];
        s0 = fmaf(a0.x,h.x, fmaf(a0.y,h.y, fmaf(a0.z,h.z, fmaf(a0.w,h.w, s0))));
        s1 = fmaf(a1.x,h.x, fmaf(a1.y,h.y, fmaf(a1.z,h.z, fmaf(a1.w,h.w, s1))));
        s2 = fmaf(a2.x,h.x, fmaf(a2.y,h.y, fmaf(a2.z,h.z, fmaf(a2.w,h.w, s2))));
        s3 = fmaf(a3.x,h.x, fmaf(a3.y,h.y, fmaf(a3.z,h.z, fmaf(a3.w,h.w, s3))));
      }
    } else {
      float h0=Hn[(size_t)j*3+0], h1=Hn[(size_t)j*3+1], h2=Hn[(size_t)j*3+2];
      s0 = hr[0][0]*h0 + hr[0][1]*h1 + hr[0][2]*h2;
      s1 = hr[1][0]*h0 + hr[1][1]*h1 + hr[1][2]*h2;
      s2 = hr[2][0]*h0 + hr[2][1]*h1 + hr[2][2]*h2;
      s3 = hr[3][0]*h0 + hr[3][1]*h1 + hr[3][2]*h2;
    }
    int m0 = A[(size_t)(r0+0)*n + j];
    int m1 = A[(size_t)(r0+1)*n + j];
    int m2 = A[(size_t)(r0+2)*n + j];
    int m3 = A[(size_t)(r0+3)*n + j];
    s0 = (m0>0) ? s0 : -1e9f;
    s1 = (m1>0) ? s1 : -1e9f;
    s2 = (m2>0) ? s2 : -1e9f;
    s3 = (m3>0) ? s3 : -1e9f;
    sc[0][j]=s0; sc[1][j]=s1; sc[2][j]=s2; sc[3][j]=s3;
    lm0=fmaxf(lm0,s0); lm1=fmaxf(lm1,s1); lm2=fmaxf(lm2,s2); lm3=fmaxf(lm3,s3);
  }
  {
    float w0=waveReduceMax(lm0), w1=waveReduceMax(lm1), w2=waveReduceMax(lm2), w3=waveReduceMax(lm3);
    if(lane==0){ redm[0][w]=w0; redm[1][w]=w1; redm[2][w]=w2; redm[3][w]=w3; }
  }
  __syncthreads();
  float m[4];
  #pragma unroll
  for(int r=0;r<4;r++) m[r] = fmaxf(fmaxf(redm[r][0],redm[r][1]), fmaxf(redm[r][2],redm[r][3]));
  __syncthreads();
  float ls0=0.f, ls1=0.f, ls2=0.f, ls3=0.f;
  for(int j=t; j<n; j+=256){
    float e0=expf(sc[0][j]-m[0]); sc[0][j]=e0; ls0+=e0;
    float e1=expf(sc[1][j]-m[1]); sc[1][j]=e1; ls1+=e1;
    float e2=expf(sc[2][j]-m[2]); sc[2][j]=e2; ls2+=e2;
    float e3=expf(sc[3][j]-m[3]); sc[3][j]=e3; ls3+=e3;
  }
  {
    float w0=waveReduceSum(ls0), w1=waveReduceSum(ls1), w2=waveReduceSum(ls2), w3=waveReduceSum(ls3);
    if(lane==0){ redm[0][w]=w0; redm[1][w]=w1; redm[2][w]=w2; redm[3][w]=w3; }
  }
  __syncthreads();   // sums visible AND all sc exp-writes visible
  float S[4];
  #pragma unroll
  for(int r=0;r<4;r++) S[r] = redm[r][0]+redm[r][1]+redm[r][2]+redm[r][3];
  if(D==GH){
    float acc0=0.f, acc1=0.f, acc2=0.f, acc3=0.f;
    const int c = lane, part = w;
    #pragma unroll 2
    for(int j=part; j<n; j+=4){
      float hv = Hn[(size_t)j*GH + c];
      acc0 = fmaf(sc[0][j], hv, acc0);
      acc1 = fmaf(sc[1][j], hv, acc1);
      acc2 = fmaf(sc[2][j], hv, acc2);
      acc3 = fmaf(sc[3][j], hv, acc3);
    }
    outp[part][0][c]=acc0; outp[part][1][c]=acc1; outp[part][2][c]=acc2; outp[part][3][c]=acc3;
    __syncthreads();
    int r = w;
    float tot = outp[0][r][lane]+outp[1][r][lane]+outp[2][r][lane]+outp[3][r][lane];
    out[(size_t)(r0+r)*GH + lane] = fmaxf(tot/S[r], 0.f);
  } else {
    float a00=0,a01=0,a02=0, a10=0,a11=0,a12=0, a20=0,a21=0,a22=0, a30=0,a31=0,a32=0;
    for(int j=t; j<n; j+=256){
      float h0=Hn[(size_t)j*3+0], h1=Hn[(size_t)j*3+1], h2=Hn[(size_t)j*3+2];
      float e0=sc[0][j], e1=sc[1][j], e2=sc[2][j], e3=sc[3][j];
      a00=fmaf(e0,h0,a00); a01=fmaf(e0,h1,a01); a02=fmaf(e0,h2,a02);
      a10=fmaf(e1,h0,a10); a11=fmaf(e1,h1,a11); a12=fmaf(e1,h2,a12);
      a20=fmaf(e2,h0,a20); a21=fmaf(e2,h1,a21); a22=fmaf(e2,h2,a22);
      a30=fmaf(e3,h0,a30); a31=fmaf(e3,h1,a31); a32=fmaf(e3,h2,a32);
    }
    float v[12] = {a00,a01,a02,a10,a11,a12,a20,a21,a22,a30,a31,a32};
    #pragma unroll
    for(int i=0;i<12;i++){
      float ws = waveReduceSum(v[i]);
      if(lane==0) out3[w][i/3][i%3] = ws;
    }
    __syncthreads();
    if(t < 4){
      int r = t;
      float t0 = out3[0][r][0]+out3[1][r][0]+out3[2][r][0]+out3[3][r][0];
      float t1 = out3[0][r][1]+out3[1][r][1]+out3[2][r][1]+out3[3][r][1];
      float t2 = out3[0][r][2]+out3[1][r][2]+out3[2][r][2]+out3[3][r][2];
      float v0 = fmaxf(t0/S[r], 0.f);
      float v1 = fmaxf(t1/S[r], 0.f);
      float v2 = fmaxf(t2/S[r], 0.f);
      if(FINAL){
        float mm = fmaxf(v0, fmaxf(v1,v2));
        float e0=expf(v0-mm), e1=expf(v1-mm), e2=expf(v2-mm);
        float ss = e0+e1+e2;
        out[(size_t)(r0+r)*3+0]=e0/ss; out[(size_t)(r0+r)*3+1]=e1/ss; out[(size_t)(r0+r)*3+2]=e2/ss;
      } else {
        out[(size_t)(r0+r)*3+0]=v0; out[(size_t)(r0+r)*3+1]=v1; out[(size_t)(r0+r)*3+2]=v2;
      }
    }
  }
}

// ---------- fuse scales + accumulate superpixel sums on finest graph ----------
__global__ void k_fuse(const int* __restrict__ s0, const int* __restrict__ s1, const int* __restrict__ s2,
                       const float* __restrict__ S0, const float* __restrict__ S1, const float* __restrict__ S2,
                       const float* __restrict__ cst, float* __restrict__ fused, float* __restrict__ spsum){
  int p = blockIdx.x*256 + threadIdx.x;
  if(p >= N_PIX) return;
  float w0=cst[0], w1=cst[1], w2=cst[2];
  int a=s0[p], b=s1[p], c=s2[p];
  #pragma unroll
  for(int e=0;e<3;e++){
    float f = w0*S0[a*3+e] + w1*S1[b*3+e] + w2*S2[c*3+e];
    fused[(size_t)p*3+e] = f;
    atomicAdd(&spsum[a*3+e], f);
  }
}

// ---------- PCR: smoothed_sp[r] = softmax(attn[r]) @ (spsum/cnt) ----------
__global__ __launch_bounds__(256) void k_pcr(const float* __restrict__ attn, const float* __restrict__ spsum,
                                             const int* __restrict__ cnt0, float* __restrict__ sm){
  __shared__ float buf[2048];
  __shared__ float red[4];
  __shared__ float r3[256][3];
  int r=blockIdx.x, t=threadIdx.x;
  float lmax=-INFINITY;
  for(int j=t;j<2000;j+=256){ float v=attn[(size_t)r*2000+j]; buf[j]=v; lmax=fmaxf(lmax,v); }
  float wm=waveReduceMax(lmax);
  if((t&63)==0) red[t>>6]=wm;
  __syncthreads();
  float m = fmaxf(fmaxf(red[0],red[1]),fmaxf(red[2],red[3]));
  __syncthreads();
  float lsum=0.f;
  for(int j=t;j<2000;j+=256){ float e=expf(buf[j]-m); buf[j]=e; lsum+=e; }
  float wsu=waveReduceSum(lsum);
  if((t&63)==0) red[t>>6]=wsu;
  __syncthreads();
  float S=red[0]+red[1]+red[2]+red[3];
  float a0=0.f,a1=0.f,a2=0.f;
  for(int j=t;j<2000;j+=256){
    float e=buf[j];
    float inv = 1.f / fmaxf((float)cnt0[j], 1.f);
    a0=fmaf(e, spsum[j*3+0]*inv, a0);
    a1=fmaf(e, spsum[j*3+1]*inv, a1);
    a2=fmaf(e, spsum[j*3+2]*inv, a2);
  }
  r3[t][0]=a0; r3[t][1]=a1; r3[t][2]=a2;
  __syncthreads();
  for(int st=128;st>0;st>>=1){
    if(t<st){ r3[t][0]+=r3[t+st][0]; r3[t][1]+=r3[t+st][1]; r3[t][2]+=r3[t+st][2]; }
    __syncthreads();
  }
  if(t==0){ sm[r*3+0]=r3[0][0]/S; sm[r*3+1]=r3[0][1]/S; sm[r*3+2]=r3[0][2]/S; }
}

// ---------- S_flat + argmax class index ----------
__global__ void k_sflat(const float* __restrict__ fused, const int* __restrict__ s0,
                        const float* __restrict__ sm, const float* __restrict__ cst,
                        float* __restrict__ Sf, int* __restrict__ ci){
  int p = blockIdx.x*256 + threadIdx.x;
  if(p >= N_PIX) return;
  float a = cst[3];
  int s = s0[p];
  float x0 = a*sm[s*3+0] + (1.f-a)*fused[(size_t)p*3+0];
  float x1 = a*sm[s*3+1] + (1.f-a)*fused[(size_t)p*3+1];
  float x2 = a*sm[s*3+2] + (1.f-a)*fused[(size_t)p*3+2];
  Sf[(size_t)p*3+0]=x0; Sf[(size_t)p*3+1]=x1; Sf[(size_t)p*3+2]=x2;
  int c=0; float b=x0;
  if(x1>b){c=1;b=x1;}
  if(x2>b){c=2;}
  ci[p]=c;
}

// ---------- weight pre-pack into MFMA B-fragment order, bf16 hi/lo ----------
__global__ void k_packw(const float* __restrict__ W, int Kreal, int Nreal, int nkt, int nnt,
                        u16* __restrict__ dhi, u16* __restrict__ dlo){
  int gid = blockIdx.x*256 + threadIdx.x;
  int total = nnt*nkt*512;
  if(gid >= total) return;
  int j = gid & 7, l = (gid>>3)&63;
  int rem = gid >> 9;               // nt*nkt + ks
  int ks = rem % nkt;
  int nt = rem / nkt;
  int k = ks*32 + (l>>4)*8 + j;
  int n = nt*16 + (l&15);
  float w = (k < Kreal && n < Nreal) ? W[(size_t)k*Nreal + n] : 0.f;
  u16 hi = f2bf(w);
  dhi[gid] = hi;
  dlo[gid] = f2bf(w - bf2f(hi));
}

// ---------- persistent MFMA MLP (156->128->128->156) + one-pass per-class exp sums ----------
// 256 blocks (1/CU), 512 threads (8 waves). Each block: 1024 px = 8 panels of 128.
// L1/L2 weight fragments preloaded into VGPRs once per block; LDS holds X panel + H panel.
// Class sums accumulate in LDS across panels; ONE global-atomic flush per block.
#define MFMA(a,b,c) __builtin_amdgcn_mfma_f32_16x16x32_bf16((a),(b),(c),0,0,0)

__global__ __launch_bounds__(512, 2) void k_mlp_mfma(
    const float* __restrict__ Y, const int* __restrict__ ci,
    const u16* __restrict__ P1h, const u16* __restrict__ P1l,
    const u16* __restrict__ P2h, const u16* __restrict__ P2l,
    const u16* __restrict__ P3h, const u16* __restrict__ P3l,
    const float* __restrict__ b1, const float* __restrict__ b2, const float* __restrict__ b3,
    float* __restrict__ gsum, float* __restrict__ gwsum){
  __shared__ u16 XH[128*168], XL[128*168];   // X panel hi/lo (43008 B each)
  __shared__ u16 HH[128*136], HL[128*136];   // h1 / h2 panel hi/lo (34816 B each)
  __shared__ float csum[480], cwsum[480];    // per-class sums [3][160]
  __shared__ int cis[128];
  const int t = threadIdx.x;
  const int lane = t & 63, w = t >> 6;        // 8 waves
  const int g = lane >> 4, r16 = lane & 15;

  // ---- per-block init ----
  for(int i=t;i<480;i+=512){ csum[i]=0.f; cwsum[i]=0.f; }

  // ---- preload L1/L2 weight fragments into VGPRs (wave w owns output ntile w) ----
  bfrag8 w1h[5], w1l[5], w2h[4], w2l[4];
  #pragma unroll
  for(int ks=0;ks<5;ks++){
    w1h[ks] = *(const bfrag8*)(P1h + ((size_t)(w*5+ks))*512 + lane*8);
    w1l[ks] = *(const bfrag8*)(P1l + ((size_t)(w*5+ks))*512 + lane*8);
  }
  #pragma unroll
  for(int ks=0;ks<4;ks++){
    w2h[ks] = *(const bfrag8*)(P2h + ((size_t)(w*4+ks))*512 + lane*8);
    w2l[ks] = *(const bfrag8*)(P2l + ((size_t)(w*4+ks))*512 + lane*8);
  }
  const int c12 = w*16 + r16;          // L1/L2 output column of this lane
  const float bv1 = b1[c12];
  const float bv2 = b2[c12];
  // L3: wave w owns ntile w always; waves 0,1 additionally own ntile 8+w
  const int c3a = w*16 + r16;          // < 128 always
  const int c3b = 128 + w*16 + r16;    // only valid for w<2 and c3b<156
  const float bv3a = b3[c3a];
  const float bv3b = (w<2 && c3b<156) ? b3[c3b] : 0.f;

  const size_t pxbase = (size_t)blockIdx.x * 1024;

  for(int it=0; it<8; ++it){
    const size_t p0 = pxbase + (size_t)it*128;

    // ---- stage X panel: 128 rows x 39 float4, bf16 hi/lo split ----
    for(int i=t;i<4992;i+=512){
      int row = i/39, q = i - row*39, c0 = q*4;
      float4 v = *(const float4*)(Y + (p0+row)*NB + c0);
      u16 h0=f2bf(v.x), h1=f2bf(v.y), h2=f2bf(v.z), h3=f2bf(v.w);
      u16 l0=f2bf(v.x-bf2f(h0)), l1=f2bf(v.y-bf2f(h1)), l2=f2bf(v.z-bf2f(h2)), l3=f2bf(v.w-bf2f(h3));
      *(unsigned*)&XH[row*168+c0]   = (unsigned)h0 | ((unsigned)h1<<16);
      *(unsigned*)&XH[row*168+c0+2] = (unsigned)h2 | ((unsigned)h3<<16);
      *(unsigned*)&XL[row*168+c0]   = (unsigned)l0 | ((unsigned)l1<<16);
      *(unsigned*)&XL[row*168+c0+2] = (unsigned)l2 | ((unsigned)l3<<16);
    }
    if(t<256){ int row=t>>1, o=156+(t&1)*2;
      *(unsigned*)&XH[row*168+o]=0u; *(unsigned*)&XL[row*168+o]=0u; }
    if(t<128) cis[t] = ci[p0+t];
    __syncthreads();

    // ---- layer 1: K=160 (5 ks), 8 m-tiles, wave w -> cols [w*16, w*16+16) ----
    {
      f32x4 acc[8];
      #pragma unroll
      for(int mt=0;mt<8;mt++) acc[mt] = (f32x4){0.f,0.f,0.f,0.f};
      #pragma unroll
      for(int ks=0;ks<5;ks++){
        #pragma unroll
        for(int mt=0;mt<8;mt++){
          bfrag8 ah = *(const bfrag8*)(XH + (mt*16+r16)*168 + g*8 + ks*32);
          bfrag8 al = *(const bfrag8*)(XL + (mt*16+r16)*168 + g*8 + ks*32);
          acc[mt]=MFMA(ah,w1h[ks],acc[mt]);
          acc[mt]=MFMA(ah,w1l[ks],acc[mt]);
          acc[mt]=MFMA(al,w1h[ks],acc[mt]);
        }
      }
      #pragma unroll
      for(int mt=0;mt<8;mt++)
        #pragma unroll
        for(int r=0;r<4;r++){
          float v = fmaxf(acc[mt][r] + bv1, 0.f);
          int row = mt*16 + g*4 + r;
          u16 h = f2bf(v);
          HH[row*136+c12] = h; HL[row*136+c12] = f2bf(v - bf2f(h));
        }
    }
    __syncthreads();

    // ---- layer 2: K=128 (4 ks); acc in regs, then overwrite H ----
    {
      f32x4 acc[8];
      #pragma unroll
      for(int mt=0;mt<8;mt++) acc[mt] = (f32x4){0.f,0.f,0.f,0.f};
      #pragma unroll
      for(int ks=0;ks<4;ks++){
        #pragma unroll
        for(int mt=0;mt<8;mt++){
          bfrag8 ah = *(const bfrag8*)(HH + (mt*16+r16)*136 + g*8 + ks*32);
          bfrag8 al = *(const bfrag8*)(HL + (mt*16+r16)*136 + g*8 + ks*32);
          acc[mt]=MFMA(ah,w2h[ks],acc[mt]);
          acc[mt]=MFMA(ah,w2l[ks],acc[mt]);
          acc[mt]=MFMA(al,w2h[ks],acc[mt]);
        }
      }
      __syncthreads();   // all waves done reading h1
      #pragma unroll
      for(int mt=0;mt<8;mt++)
        #pragma unroll
        for(int r=0;r<4;r++){
          float v = fmaxf(acc[mt][r] + bv2, 0.f);
          int row = mt*16 + g*4 + r;
          u16 h = f2bf(v);
          HH[row*136+c12] = h; HL[row*136+c12] = f2bf(v - bf2f(h));
        }
    }
    __syncthreads();

    // ---- layer 3 + epilogue: ntile w (cols w*16..), waves 0,1 also ntile 8+w ----
    {
      // primary ntile: nt = w
      bfrag8 b3h[4], b3l[4];
      #pragma unroll
      for(int ks=0;ks<4;ks++){
        b3h[ks] = *(const bfrag8*)(P3h + ((size_t)(w*4+ks))*512 + lane*8);
        b3l[ks] = *(const bfrag8*)(P3l + ((size_t)(w*4+ks))*512 + lane*8);
      }
      f32x4 acc[8];
      #pragma unroll
      for(int mt=0;mt<8;mt++) acc[mt] = (f32x4){0.f,0.f,0.f,0.f};
      #pragma unroll
      for(int ks=0;ks<4;ks++){
        #pragma unroll
        for(int mt=0;mt<8;mt++){
          bfrag8 ah = *(const bfrag8*)(HH + (mt*16+r16)*136 + g*8 + ks*32);
          bfrag8 al = *(const bfrag8*)(HL + (mt*16+r16)*136 + g*8 + ks*32);
          acc[mt]=MFMA(ah,b3h[ks],acc[mt]);
          acc[mt]=MFMA(ah,b3l[ks],acc[mt]);
          acc[mt]=MFMA(al,b3h[ks],acc[mt]);
        }
      }
      #pragma unroll
      for(int mt=0;mt<8;mt++)
        #pragma unroll
        for(int r=0;r<4;r++){
          int p = mt*16 + g*4 + r;
          float v = acc[mt][r] + bv3a;
          float e = expf(v);
          float y = bf2f(XH[p*168+c3a]) + bf2f(XL[p*168+c3a]);
          int cls = cis[p];
          atomicAdd(&csum[cls*160 + c3a], e);
          atomicAdd(&cwsum[cls*160 + c3a], e*y);
        }
      // secondary ntile for waves 0,1: nt = 8+w (cols 128..159, real < 156)
      if(w < 2){
        bfrag8 c3h[4], c3l[4];
        #pragma unroll
        for(int ks=0;ks<4;ks++){
          c3h[ks] = *(const bfrag8*)(P3h + ((size_t)((8+w)*4+ks))*512 + lane*8);
          c3l[ks] = *(const bfrag8*)(P3l + ((size_t)((8+w)*4+ks))*512 + lane*8);
        }
        f32x4 acc2[8];
        #pragma unroll
        for(int mt=0;mt<8;mt++) acc2[mt] = (f32x4){0.f,0.f,0.f,0.f};
        #pragma unroll
        for(int ks=0;ks<4;ks++){
          #pragma unroll
          for(int mt=0;mt<8;mt++){
            bfrag8 ah = *(const bfrag8*)(HH + (mt*16+r16)*136 + g*8 + ks*32);
            bfrag8 al = *(const bfrag8*)(HL + (mt*16+r16)*136 + g*8 + ks*32);
            acc2[mt]=MFMA(ah,c3h[ks],acc2[mt]);
            acc2[mt]=MFMA(ah,c3l[ks],acc2[mt]);
            acc2[mt]=MFMA(al,c3h[ks],acc2[mt]);
          }
        }
        if(c3b < 156){
          #pragma unroll
          for(int mt=0;mt<8;mt++)
            #pragma unroll
            for(int r=0;r<4;r++){
              int p = mt*16 + g*4 + r;
              float v = acc2[mt][r] + bv3b;
              float e = expf(v);
              float y = bf2f(XH[p*168+c3b]) + bf2f(XL[p*168+c3b]);
              int cls = cis[p];
              atomicAdd(&csum[cls*160 + c3b], e);
              atomicAdd(&cwsum[cls*160 + c3b], e*y);
            }
        }
      }
    }
    __syncthreads();   // epilogue done reading X/H before next stage overwrites
  }

  // ---- one global flush per block ----
  float* gs = gsum  + (size_t)blockIdx.x*480;
  float* gw = gwsum + (size_t)blockIdx.x*480;
  for(int i=t;i<480;i+=512){
    atomicAdd(&gs[i], csum[i]);
    atomicAdd(&gw[i], cwsum[i]);
  }
}

__global__ void k_finalM(const float* __restrict__ gsump, const float* __restrict__ gwsump, float* __restrict__ M){
  int e = blockIdx.x*256 + threadIdx.x;
  if(e < 468){
    int cls = e/156, c = e - cls*156;
    float s=0.f, wv=0.f;
    for(int k=0;k<256;k++){ s += gsump[(size_t)k*480 + cls*160 + c]; wv += gwsump[(size_t)k*480 + cls*160 + c]; }
    M[e] = (s > 0.f) ? (wv / fmaxf(s, 1e-30f)) : 0.f;
  }
}

// ---------- Y_hat = S_flat @ M, float4 stores ----------
__global__ void k_yhat4(const float* __restrict__ Sf, const float* __restrict__ M, float4* __restrict__ out){
  unsigned idx = blockIdx.x*256u + threadIdx.x;   // N_PIX*39 float4s, grid exact
  unsigned p = idx / 39u, q = idx - p*39u;
  unsigned c0 = q*4u;
  float4 m0 = *(const float4*)(M + c0);
  float4 m1 = *(const float4*)(M + 156 + c0);
  float4 m2 = *(const float4*)(M + 312 + c0);
  float s0 = Sf[(size_t)p*3+0], s1 = Sf[(size_t)p*3+1], s2 = Sf[(size_t)p*3+2];
  float4 r;
  r.x = s0*m0.x + s1*m1.x + s2*m2.x;
  r.y = s0*m0.y + s1*m1.y + s2*m2.y;
  r.z = s0*m0.z + s1*m1.z + s2*m2.z;
  r.w = s0*m0.w + s1*m1.w + s2*m2.w;
  out[idx] = r;
}

extern "C" void kernel_launch(void* const* d_in, const int* in_sizes, int n_in,
                              void* d_out, int out_size, void* d_ws, size_t ws_size,
                              hipStream_t stream){
  const float* Y    = (const float*)d_in[0];
  const int*   seg0 = (const int*)d_in[1];
  const int*   A0   = (const int*)d_in[2];
  const int*   seg1 = (const int*)d_in[3];
  const int*   A1   = (const int*)d_in[4];
  const int*   seg2 = (const int*)d_in[5];
  const int*   A2   = (const int*)d_in[6];
  const float* attn = (const float*)d_in[7];
  const float* alpha= (const float*)d_in[8];
  const float* sw   = (const float*)d_in[9];
  const float* W1a[3] = {(const float*)d_in[10], (const float*)d_in[14], (const float*)d_in[18]};
  const float* b1a[3] = {(const float*)d_in[11], (const float*)d_in[15], (const float*)d_in[19]};
  const float* W2a[3] = {(const float*)d_in[12], (const float*)d_in[16], (const float*)d_in[20]};
  const float* b2a[3] = {(const float*)d_in[13], (const float*)d_in[17], (const float*)d_in[21]};
  const float* Wm1=(const float*)d_in[22]; const float* bm1=(const float*)d_in[23];
  const float* Wm2=(const float*)d_in[24]; const float* bm2=(const float*)d_in[25];
  const float* Wm3=(const float*)d_in[26]; const float* bm3=(const float*)d_in[27];
  float* out = (float*)d_out;

  const int nseg[3] = {2000, 1000, 500};
  const int* Aarr[3]   = {A0, A1, A2};

  char* base = (char*)d_ws;
  size_t off = 0;
  auto alloc = [&](size_t bytes)->char*{
    char* r = base + off;
    off += (bytes + 255) & ~(size_t)255;
    return r;
  };
  int* cnt[3]; int* offs[3]; int* cur[3]; int* lst[3]; float* X[3]; float* Ss[3];
  for(int i=0;i<3;i++) cnt[i]  = (int*)alloc((size_t)nseg[i]*4);
  for(int i=0;i<3;i++) offs[i] = (int*)alloc((size_t)nseg[i]*4);
  for(int i=0;i<3;i++) cur[i]  = (int*)alloc((size_t)nseg[i]*4);
  for(int i=0;i<3;i++) lst[i]  = (int*)alloc((size_t)N_PIX*4);
  for(int i=0;i<3;i++) X[i]    = (float*)alloc((size_t)nseg[i]*NB*4);
  float* Hn   = (float*)alloc((size_t)2000*64*4);
  float* x1b  = (float*)alloc((size_t)2000*64*4);
  float* Hn2  = (float*)alloc((size_t)2000*3*4);
  for(int i=0;i<3;i++) Ss[i]   = (float*)alloc((size_t)nseg[i]*3*4);
  float* cst   = (float*)alloc(64);
  float* fused = (float*)alloc((size_t)N_PIX*3*4);
  float* spsum = (float*)alloc((size_t)2000*3*4);
  float* smth  = (float*)alloc((size_t)2000*3*4);
  float* Sf    = (float*)alloc((size_t)N_PIX*3*4);
  int*   ci    = (int*)alloc((size_t)N_PIX*4);
  u16* P1h = (u16*)alloc((size_t)20480*2); u16* P1l = (u16*)alloc((size_t)20480*2);
  u16* P2h = (u16*)alloc((size_t)16384*2); u16* P2l = (u16*)alloc((size_t)16384*2);
  u16* P3h = (u16*)alloc((size_t)20480*2); u16* P3l = (u16*)alloc((size_t)20480*2);
  float* gsump  = (float*)alloc((size_t)256*480*4);
  float* gwsump = (float*)alloc((size_t)256*480*4);
  float* Mbuf   = (float*)alloc((size_t)480*4);

  // per-call re-init of all accumulators (replay/poison safe)
  for(int i=0;i<3;i++) hipMemsetAsync(cnt[i], 0, (size_t)nseg[i]*4, stream);
  hipMemsetAsync(spsum, 0, (size_t)2000*3*4, stream);
  hipMemsetAsync(gsump, 0, (size_t)256*480*4, stream);
  hipMemsetAsync(gwsump, 0, (size_t)256*480*4, stream);
  k_prep<<<1,64,0,stream>>>(sw, alpha, cst);

  // weight pre-pack (independent of everything else)
  k_packw<<<(8*5*512+255)/256,256,0,stream>>>(Wm1, 156, 128, 5, 8, P1h, P1l);
  k_packw<<<(8*4*512+255)/256,256,0,stream>>>(Wm2, 128, 128, 4, 8, P2h, P2l);
  k_packw<<<(10*4*512+255)/256,256,0,stream>>>(Wm3, 128, 156, 4, 10, P3h, P3l);

  // CSR + segment means (all 3 scales fused)
  k_count<<<N_PIX/256,256,0,stream>>>(seg0,seg1,seg2,cnt[0],cnt[1],cnt[2]);
  k_scan<<<3,256,0,stream>>>(cnt[0],cnt[1],cnt[2],offs[0],offs[1],offs[2],cur[0],cur[1],cur[2]);
  k_fill<<<N_PIX/256,256,0,stream>>>(seg0,seg1,seg2,cur[0],cur[1],cur[2],lst[0],lst[1],lst[2]);
  k_segmean3<<<3500,128,0,stream>>>(Y,
      offs[0],cnt[0],lst[0],X[0],
      offs[1],cnt[1],lst[1],X[1],
      offs[2],cnt[2],lst[2],X[2]);

  // Multi-scale GAT encoder
  for(int i=0;i<3;i++){
    int n = nseg[i];
    k_linear<<<(n*64+255)/256,256,0,stream>>>(X[i],  W1a[i], b1a[i], Hn,  n, NB, 64);
    k_attn4<64,false><<<n/4,256,0,stream>>>(Hn, Aarr[i], x1b, n);
    k_linear<<<(n*3+255)/256,256,0,stream>>>(x1b, W2a[i], b2a[i], Hn2, n, 64, 3);
    k_attn4<3,true><<<n/4,256,0,stream>>>(Hn2, Aarr[i], Ss[i], n);
  }

  // fuse + PCR
  k_fuse<<<N_PIX/256,256,0,stream>>>(seg0,seg1,seg2,Ss[0],Ss[1],Ss[2],cst,fused,spsum);
  k_pcr<<<2000,256,0,stream>>>(attn, spsum, cnt[0], smth);
  k_sflat<<<N_PIX/256,256,0,stream>>>(fused, seg0, smth, cst, Sf, ci);

  // ACDE: persistent-block MFMA MLP + per-class exp sums
  k_mlp_mfma<<<256,512,0,stream>>>(Y, ci, P1h,P1l,P2h,P2l,P3h,P3l, bm1,bm2,bm3, gsump, gwsump);
  k_finalM<<<2,256,0,stream>>>(gsump, gwsump, Mbuf);
  k_yhat4<<<(N_PIX/256)*39,256,0,stream>>>(Sf, Mbuf, (float4*)out);
  (void)in_sizes; (void)n_in; (void)out_size;
}

// Round 7
// 1406.479 us; speedup vs baseline: 1.0579x; 1.0579x over previous
//
#include <hip/hip_runtime.h>
#include <math.h>

#define N_PIX (512*512)
#define NB 156
#define GH 64

typedef unsigned short u16;
typedef __attribute__((ext_vector_type(8))) short bfrag8;   // 8 bf16 = 4 VGPRs
typedef __attribute__((ext_vector_type(4))) float f32x4;    // MFMA accumulator

// ---------- bf16 split helpers (RNE) ----------
__device__ __forceinline__ u16 f2bf(float x){
  unsigned u = __float_as_uint(x);
  unsigned r = (u + 0x7FFFu + ((u >> 16) & 1u)) >> 16;
  return (u16)r;
}
__device__ __forceinline__ float bf2f(u16 h){
  return __uint_as_float(((unsigned)h) << 16);
}

__device__ __forceinline__ float waveReduceMax(float v){
  #pragma unroll
  for(int o=32;o>0;o>>=1) v = fmaxf(v, __shfl_down(v, o, 64));
  return v;
}
__device__ __forceinline__ float waveReduceSum(float v){
  #pragma unroll
  for(int o=32;o>0;o>>=1) v += __shfl_down(v, o, 64);
  return v;
}

// ---------- derived constants: softmax(scale_weights), clip(alpha) ----------
__global__ void k_prep(const float* __restrict__ sw, const float* __restrict__ alpha, float* __restrict__ cst){
  if(threadIdx.x==0 && blockIdx.x==0){
    float m = fmaxf(sw[0], fmaxf(sw[1], sw[2]));
    float e0=expf(sw[0]-m), e1=expf(sw[1]-m), e2=expf(sw[2]-m);
    float s = e0+e1+e2;
    cst[0]=e0/s; cst[1]=e1/s; cst[2]=e2/s;
    cst[3]=fminf(fmaxf(alpha[0],0.f),1.f);
  }
}

// ---------- CSR build ----------
__global__ void k_count(const int* __restrict__ s0, const int* __restrict__ s1, const int* __restrict__ s2,
                        int* c0, int* c1, int* c2){
  int p = blockIdx.x*256 + threadIdx.x;
  if(p < N_PIX){
    atomicAdd(&c0[s0[p]],1);
    atomicAdd(&c1[s1[p]],1);
    atomicAdd(&c2[s2[p]],1);
  }
}

__global__ __launch_bounds__(256) void k_scan(const int* __restrict__ c0, const int* __restrict__ c1, const int* __restrict__ c2,
                       int* o0, int* o1, int* o2, int* u0, int* u1, int* u2){
  const int* cnt; int* offs; int* cur; int n;
  if(blockIdx.x==0){ cnt=c0; offs=o0; cur=u0; n=2000; }
  else if(blockIdx.x==1){ cnt=c1; offs=o1; cur=u1; n=1000; }
  else { cnt=c2; offs=o2; cur=u2; n=500; }
  __shared__ int l[2048];
  __shared__ int cs[256];
  int t = threadIdx.x;
  for(int i=t;i<2048;i+=256) l[i] = (i<n) ? cnt[i] : 0;
  __syncthreads();
  int s = 0;
  #pragma unroll
  for(int j=0;j<8;j++) s += l[t*8+j];
  cs[t] = s;
  __syncthreads();
  for(int d=1; d<256; d<<=1){
    int v = (t>=d) ? cs[t-d] : 0;
    __syncthreads();
    cs[t] += v;
    __syncthreads();
  }
  int run = cs[t] - s;
  for(int j=0;j<8;j++){
    int idx = t*8+j;
    int o = run;
    run += l[idx];
    if(idx < n){ offs[idx] = o; cur[idx] = o; }
  }
}

__global__ void k_fill(const int* __restrict__ s0, const int* __restrict__ s1, const int* __restrict__ s2,
                       int* u0, int* u1, int* u2, int* L0, int* L1, int* L2){
  int p = blockIdx.x*256 + threadIdx.x;
  if(p < N_PIX){
    int a = atomicAdd(&u0[s0[p]],1); L0[a] = p;
    int b = atomicAdd(&u1[s1[p]],1); L1[b] = p;
    int c = atomicAdd(&u2[s2[p]],1); L2[c] = p;
  }
}

// ---------- fused segment mean over all 3 scales ----------
__global__ __launch_bounds__(128) void k_segmean3(const float* __restrict__ Y,
    const int* __restrict__ o0, const int* __restrict__ c0, const int* __restrict__ l0, float* __restrict__ X0,
    const int* __restrict__ o1, const int* __restrict__ c1, const int* __restrict__ l1, float* __restrict__ X1,
    const int* __restrict__ o2, const int* __restrict__ c2, const int* __restrict__ l2, float* __restrict__ X2){
  int b = blockIdx.x;
  const int *offs, *cnt, *list; float* X; int s;
  if(b < 2000){ s=b;      offs=o0; cnt=c0; list=l0; X=X0; }
  else if(b < 3000){ s=b-2000; offs=o1; cnt=c1; list=l1; X=X1; }
  else { s=b-3000; offs=o2; cnt=c2; list=l2; X=X2; }
  int t = threadIdx.x;
  int n = cnt[s], st = offs[s];
  if(t < 78){
    float ax=0.f, ay=0.f;
    int q = 0;
    for(; q+4<=n; q+=4){
      int p0 = list[st+q], p1 = list[st+q+1], p2 = list[st+q+2], p3 = list[st+q+3];
      float2 v0 = *(const float2*)(Y + (size_t)p0*NB + t*2);
      float2 v1 = *(const float2*)(Y + (size_t)p1*NB + t*2);
      float2 v2 = *(const float2*)(Y + (size_t)p2*NB + t*2);
      float2 v3 = *(const float2*)(Y + (size_t)p3*NB + t*2);
      ax += (v0.x + v1.x) + (v2.x + v3.x);
      ay += (v0.y + v1.y) + (v2.y + v3.y);
    }
    for(; q<n; q++){
      int p0 = list[st+q];
      float2 v0 = *(const float2*)(Y + (size_t)p0*NB + t*2);
      ax += v0.x; ay += v0.y;
    }
    float inv = 1.f / fmaxf((float)n, 1.f);
    float2 r; r.x = ax*inv; r.y = ay*inv;
    *(float2*)(X + (size_t)s*NB + t*2) = r;
  }
}

// ---------- generic small linear: out[n,D] = X[n,K]@W[K,D]+b ----------
__global__ void k_linear(const float* __restrict__ X, const float* __restrict__ W, const float* __restrict__ bias,
                         float* __restrict__ out, int n, int K, int D){
  int gid = blockIdx.x*256 + threadIdx.x;
  if(gid >= n*D) return;
  int r = gid / D, c = gid - r*D;
  const float* xr = X + (size_t)r*K;
  float acc = bias[c];
  for(int k=0;k<K;k++) acc = fmaf(xr[k], W[(size_t)k*D + c], acc);
  out[gid] = acc;
}

// ---------- GAT masked attention, 4 rows per block ----------
template<int D, bool FINAL>
__global__ __launch_bounds__(256) void k_attn4(const float* __restrict__ Hn, const int* __restrict__ A,
                                               float* __restrict__ out, int n){
  __shared__ float sc[4][2048];
  __shared__ float hr[4][GH];
  __shared__ float redm[4][4];
  __shared__ float outp[4][4][GH];   // part, r, c (D==64)
  __shared__ float out3[4][4][4];    // wave, r, c (D==3)
  const int t = threadIdx.x, w = t>>6, lane = t&63;
  const int r0 = blockIdx.x*4;
  if(D==GH){
    hr[w][lane] = Hn[(size_t)(r0 + w)*GH + lane];
  } else {
    if(t < 12) hr[t/3][t%3] = Hn[(size_t)(r0 + t/3)*3 + (t%3)];
  }
  __syncthreads();
  float lm0=-INFINITY, lm1=-INFINITY, lm2=-INFINITY, lm3=-INFINITY;
  for(int j=t; j<n; j+=256){
    float s0,s1,s2,s3;
    if(D==GH){
      const float4* hj = (const float4*)(Hn + (size_t)j*GH);
      s0=s1=s2=s3=0.f;
      #pragma unroll
      for(int k4=0;k4<GH/4;k4++){
        float4 h  = hj[k4];
        float4 a0 = *(const float4*)&hr[0][k4*4];
        float4 a1 = *(const float4*)&hr[1][k4*4];
        float4 a2 = *(const float4*)&hr[2][k4*4];
        float4 a3 = *(const float4*)&hr[3][k4*4];
        s0 = fmaf(a0.x,h.x, fmaf(a0.y,h.y, fmaf(a0.z,h.z, fmaf(a0.w,h.w, s0))));
        s1 = fmaf(a1.x,h.x, fmaf(a1.y,h.y, fmaf(a1.z,h.z, fmaf(a1.w,h.w, s1))));
        s2 = fmaf(a2.x,h.x, fmaf(a2.y,h.y, fmaf(a2.z,h.z, fmaf(a2.w,h.w, s2))));
        s3 = fmaf(a3.x,h.x, fmaf(a3.y,h.y, fmaf(a3.z,h.z, fmaf(a3.w,h.w, s3))));
      }
    } else {
      float h0=Hn[(size_t)j*3+0], h1=Hn[(size_t)j*3+1], h2=Hn[(size_t)j*3+2];
      s0 = hr[0][0]*h0 + hr[0][1]*h1 + hr[0][2]*h2;
      s1 = hr[1][0]*h0 + hr[1][1]*h1 + hr[1][2]*h2;
      s2 = hr[2][0]*h0 + hr[2][1]*h1 + hr[2][2]*h2;
      s3 = hr[3][0]*h0 + hr[3][1]*h1 + hr[3][2]*h2;
    }
    int m0 = A[(size_t)(r0+0)*n + j];
    int m1 = A[(size_t)(r0+1)*n + j];
    int m2 = A[(size_t)(r0+2)*n + j];
    int m3 = A[(size_t)(r0+3)*n + j];
    s0 = (m0>0) ? s0 : -1e9f;
    s1 = (m1>0) ? s1 : -1e9f;
    s2 = (m2>0) ? s2 : -1e9f;
    s3 = (m3>0) ? s3 : -1e9f;
    sc[0][j]=s0; sc[1][j]=s1; sc[2][j]=s2; sc[3][j]=s3;
    lm0=fmaxf(lm0,s0); lm1=fmaxf(lm1,s1); lm2=fmaxf(lm2,s2); lm3=fmaxf(lm3,s3);
  }
  {
    float w0=waveReduceMax(lm0), w1=waveReduceMax(lm1), w2=waveReduceMax(lm2), w3=waveReduceMax(lm3);
    if(lane==0){ redm[0][w]=w0; redm[1][w]=w1; redm[2][w]=w2; redm[3][w]=w3; }
  }
  __syncthreads();
  float m[4];
  #pragma unroll
  for(int r=0;r<4;r++) m[r] = fmaxf(fmaxf(redm[r][0],redm[r][1]), fmaxf(redm[r][2],redm[r][3]));
  __syncthreads();
  float ls0=0.f, ls1=0.f, ls2=0.f, ls3=0.f;
  for(int j=t; j<n; j+=256){
    float e0=expf(sc[0][j]-m[0]); sc[0][j]=e0; ls0+=e0;
    float e1=expf(sc[1][j]-m[1]); sc[1][j]=e1; ls1+=e1;
    float e2=expf(sc[2][j]-m[2]); sc[2][j]=e2; ls2+=e2;
    float e3=expf(sc[3][j]-m[3]); sc[3][j]=e3; ls3+=e3;
  }
  {
    float w0=waveReduceSum(ls0), w1=waveReduceSum(ls1), w2=waveReduceSum(ls2), w3=waveReduceSum(ls3);
    if(lane==0){ redm[0][w]=w0; redm[1][w]=w1; redm[2][w]=w2; redm[3][w]=w3; }
  }
  __syncthreads();   // sums visible AND all sc exp-writes visible
  float S[4];
  #pragma unroll
  for(int r=0;r<4;r++) S[r] = redm[r][0]+redm[r][1]+redm[r][2]+redm[r][3];
  if(D==GH){
    float acc0=0.f, acc1=0.f, acc2=0.f, acc3=0.f;
    const int c = lane, part = w;
    #pragma unroll 2
    for(int j=part; j<n; j+=4){
      float hv = Hn[(size_t)j*GH + c];
      acc0 = fmaf(sc[0][j], hv, acc0);
      acc1 = fmaf(sc[1][j], hv, acc1);
      acc2 = fmaf(sc[2][j], hv, acc2);
      acc3 = fmaf(sc[3][j], hv, acc3);
    }
    outp[part][0][c]=acc0; outp[part][1][c]=acc1; outp[part][2][c]=acc2; outp[part][3][c]=acc3;
    __syncthreads();
    int r = w;
    float tot = outp[0][r][lane]+outp[1][r][lane]+outp[2][r][lane]+outp[3][r][lane];
    out[(size_t)(r0+r)*GH + lane] = fmaxf(tot/S[r], 0.f);
  } else {
    float a00=0,a01=0,a02=0, a10=0,a11=0,a12=0, a20=0,a21=0,a22=0, a30=0,a31=0,a32=0;
    for(int j=t; j<n; j+=256){
      float h0=Hn[(size_t)j*3+0], h1=Hn[(size_t)j*3+1], h2=Hn[(size_t)j*3+2];
      float e0=sc[0][j], e1=sc[1][j], e2=sc[2][j], e3=sc[3][j];
      a00=fmaf(e0,h0,a00); a01=fmaf(e0,h1,a01); a02=fmaf(e0,h2,a02);
      a10=fmaf(e1,h0,a10); a11=fmaf(e1,h1,a11); a12=fmaf(e1,h2,a12);
      a20=fmaf(e2,h0,a20); a21=fmaf(e2,h1,a21); a22=fmaf(e2,h2,a22);
      a30=fmaf(e3,h0,a30); a31=fmaf(e3,h1,a31); a32=fmaf(e3,h2,a32);
    }
    float v[12] = {a00,a01,a02,a10,a11,a12,a20,a21,a22,a30,a31,a32};
    #pragma unroll
    for(int i=0;i<12;i++){
      float ws = waveReduceSum(v[i]);
      if(lane==0) out3[w][i/3][i%3] = ws;
    }
    __syncthreads();
    if(t < 4){
      int r = t;
      float t0 = out3[0][r][0]+out3[1][r][0]+out3[2][r][0]+out3[3][r][0];
      float t1 = out3[0][r][1]+out3[1][r][1]+out3[2][r][1]+out3[3][r][1];
      float t2 = out3[0][r][2]+out3[1][r][2]+out3[2][r][2]+out3[3][r][2];
      float v0 = fmaxf(t0/S[r], 0.f);
      float v1 = fmaxf(t1/S[r], 0.f);
      float v2 = fmaxf(t2/S[r], 0.f);
      if(FINAL){
        float mm = fmaxf(v0, fmaxf(v1,v2));
        float e0=expf(v0-mm), e1=expf(v1-mm), e2=expf(v2-mm);
        float ss = e0+e1+e2;
        out[(size_t)(r0+r)*3+0]=e0/ss; out[(size_t)(r0+r)*3+1]=e1/ss; out[(size_t)(r0+r)*3+2]=e2/ss;
      } else {
        out[(size_t)(r0+r)*3+0]=v0; out[(size_t)(r0+r)*3+1]=v1; out[(size_t)(r0+r)*3+2]=v2;
      }
    }
  }
}

// ---------- fuse scales + accumulate superpixel sums on finest graph ----------
__global__ void k_fuse(const int* __restrict__ s0, const int* __restrict__ s1, const int* __restrict__ s2,
                       const float* __restrict__ S0, const float* __restrict__ S1, const float* __restrict__ S2,
                       const float* __restrict__ cst, float* __restrict__ fused, float* __restrict__ spsum){
  int p = blockIdx.x*256 + threadIdx.x;
  if(p >= N_PIX) return;
  float w0=cst[0], w1=cst[1], w2=cst[2];
  int a=s0[p], b=s1[p], c=s2[p];
  #pragma unroll
  for(int e=0;e<3;e++){
    float f = w0*S0[a*3+e] + w1*S1[b*3+e] + w2*S2[c*3+e];
    fused[(size_t)p*3+e] = f;
    atomicAdd(&spsum[a*3+e], f);
  }
}

// ---------- PCR: smoothed_sp[r] = softmax(attn[r]) @ (spsum/cnt) ----------
__global__ __launch_bounds__(256) void k_pcr(const float* __restrict__ attn, const float* __restrict__ spsum,
                                             const int* __restrict__ cnt0, float* __restrict__ sm){
  __shared__ float buf[2048];
  __shared__ float red[4];
  __shared__ float r3[256][3];
  int r=blockIdx.x, t=threadIdx.x;
  float lmax=-INFINITY;
  for(int j=t;j<2000;j+=256){ float v=attn[(size_t)r*2000+j]; buf[j]=v; lmax=fmaxf(lmax,v); }
  float wm=waveReduceMax(lmax);
  if((t&63)==0) red[t>>6]=wm;
  __syncthreads();
  float m = fmaxf(fmaxf(red[0],red[1]),fmaxf(red[2],red[3]));
  __syncthreads();
  float lsum=0.f;
  for(int j=t;j<2000;j+=256){ float e=expf(buf[j]-m); buf[j]=e; lsum+=e; }
  float wsu=waveReduceSum(lsum);
  if((t&63)==0) red[t>>6]=wsu;
  __syncthreads();
  float S=red[0]+red[1]+red[2]+red[3];
  float a0=0.f,a1=0.f,a2=0.f;
  for(int j=t;j<2000;j+=256){
    float e=buf[j];
    float inv = 1.f / fmaxf((float)cnt0[j], 1.f);
    a0=fmaf(e, spsum[j*3+0]*inv, a0);
    a1=fmaf(e, spsum[j*3+1]*inv, a1);
    a2=fmaf(e, spsum[j*3+2]*inv, a2);
  }
  r3[t][0]=a0; r3[t][1]=a1; r3[t][2]=a2;
  __syncthreads();
  for(int st=128;st>0;st>>=1){
    if(t<st){ r3[t][0]+=r3[t+st][0]; r3[t][1]+=r3[t+st][1]; r3[t][2]+=r3[t+st][2]; }
    __syncthreads();
  }
  if(t==0){ sm[r*3+0]=r3[0][0]/S; sm[r*3+1]=r3[0][1]/S; sm[r*3+2]=r3[0][2]/S; }
}

// ---------- S_flat + argmax class index ----------
__global__ void k_sflat(const float* __restrict__ fused, const int* __restrict__ s0,
                        const float* __restrict__ sm, const float* __restrict__ cst,
                        float* __restrict__ Sf, int* __restrict__ ci){
  int p = blockIdx.x*256 + threadIdx.x;
  if(p >= N_PIX) return;
  float a = cst[3];
  int s = s0[p];
  float x0 = a*sm[s*3+0] + (1.f-a)*fused[(size_t)p*3+0];
  float x1 = a*sm[s*3+1] + (1.f-a)*fused[(size_t)p*3+1];
  float x2 = a*sm[s*3+2] + (1.f-a)*fused[(size_t)p*3+2];
  Sf[(size_t)p*3+0]=x0; Sf[(size_t)p*3+1]=x1; Sf[(size_t)p*3+2]=x2;
  int c=0; float b=x0;
  if(x1>b){c=1;b=x1;}
  if(x2>b){c=2;}
  ci[p]=c;
}

// ---------- weight pre-pack into MFMA B-fragment order, bf16 hi/lo ----------
__global__ void k_packw(const float* __restrict__ W, int Kreal, int Nreal, int nkt, int nnt,
                        u16* __restrict__ dhi, u16* __restrict__ dlo){
  int gid = blockIdx.x*256 + threadIdx.x;
  int total = nnt*nkt*512;
  if(gid >= total) return;
  int j = gid & 7, l = (gid>>3)&63;
  int rem = gid >> 9;               // nt*nkt + ks
  int ks = rem % nkt;
  int nt = rem / nkt;
  int k = ks*32 + (l>>4)*8 + j;
  int n = nt*16 + (l&15);
  float w = (k < Kreal && n < Nreal) ? W[(size_t)k*Nreal + n] : 0.f;
  u16 hi = f2bf(w);
  dhi[gid] = hi;
  dlo[gid] = f2bf(w - bf2f(hi));
}

// ---------- MFMA MLP (156->128->128->156), r5 structure + register B-frag double-buffering ----------
// 32 px/block, 256 threads (4 waves), LDS aliased X[32][168] -> A[32][136]. VGPR cap 128.
#define MFMA(a,b,c) __builtin_amdgcn_mfma_f32_16x16x32_bf16((a),(b),(c),0,0,0)

__global__ __launch_bounds__(256, 4) void k_mlp_mfma(
    const float* __restrict__ Y, const int* __restrict__ ci,
    const u16* __restrict__ P1h, const u16* __restrict__ P1l,
    const u16* __restrict__ P2h, const u16* __restrict__ P2l,
    const u16* __restrict__ P3h, const u16* __restrict__ P3l,
    const float* __restrict__ b1, const float* __restrict__ b2, const float* __restrict__ b3,
    float* __restrict__ gsum, float* __restrict__ gwsum){
  __shared__ u16 SH[32*168];                 // X-hi [32][168]  ->  A-hi [32][136]
  __shared__ u16 SL[32*168];                 // X-lo            ->  A-lo
  __shared__ float csum[480], cwsum[480];    // per-class partial sums [3][160]
  __shared__ int cis[32];
  const int t = threadIdx.x;
  const int lane = t & 63, w = t >> 6;
  const int g = lane >> 4, r16 = lane & 15;
  const size_t p0 = (size_t)blockIdx.x * 32;

  for(int i=t;i<480;i+=256){ csum[i]=0.f; cwsum[i]=0.f; }
  if(t<32) cis[t] = ci[p0+t];
  // stage Y tile: 32 rows x 39 float4, split to bf16 hi/lo, packed u32 LDS writes
  for(int i=t;i<1248;i+=256){
    int row = i/39, q = i - row*39, c0 = q*4;
    float4 v = *(const float4*)(Y + (p0+row)*NB + c0);
    u16 h0=f2bf(v.x), h1=f2bf(v.y), h2=f2bf(v.z), h3=f2bf(v.w);
    u16 l0=f2bf(v.x-bf2f(h0)), l1=f2bf(v.y-bf2f(h1)), l2=f2bf(v.z-bf2f(h2)), l3=f2bf(v.w-bf2f(h3));
    *(unsigned*)&SH[row*168+c0]   = (unsigned)h0 | ((unsigned)h1<<16);
    *(unsigned*)&SH[row*168+c0+2] = (unsigned)h2 | ((unsigned)h3<<16);
    *(unsigned*)&SL[row*168+c0]   = (unsigned)l0 | ((unsigned)l1<<16);
    *(unsigned*)&SL[row*168+c0+2] = (unsigned)l2 | ((unsigned)l3<<16);
  }
  if(t<64){ int row=t>>1, o=156+(t&1)*2;
    *(unsigned*)&SH[row*168+o]=0u; *(unsigned*)&SL[row*168+o]=0u; }
  __syncthreads();

  // ---- layer 1: K=160 (5 ks), N=128; wave w -> ntiles {w, w+4}; B-frags double-buffered ----
  {
    f32x4 acc[2][2];
    #pragma unroll
    for(int u=0;u<2;u++)
      #pragma unroll
      for(int mt=0;mt<2;mt++) acc[u][mt] = (f32x4){0.f,0.f,0.f,0.f};
    const u16* b0h = P1h + ((size_t)(w*5))*512 + lane*8;
    const u16* b0l = P1l + ((size_t)(w*5))*512 + lane*8;
    const u16* b1p = P1h + ((size_t)((w+4)*5))*512 + lane*8;
    const u16* b1lp= P1l + ((size_t)((w+4)*5))*512 + lane*8;
    bfrag8 cbh0 = *(const bfrag8*)(b0h);
    bfrag8 cbl0 = *(const bfrag8*)(b0l);
    bfrag8 cbh1 = *(const bfrag8*)(b1p);
    bfrag8 cbl1 = *(const bfrag8*)(b1lp);
    #pragma unroll
    for(int ks=0;ks<5;ks++){
      bfrag8 bh0=cbh0, bl0=cbl0, bh1=cbh1, bl1=cbl1;
      if(ks<4){
        cbh0 = *(const bfrag8*)(b0h + (ks+1)*512);
        cbl0 = *(const bfrag8*)(b0l + (ks+1)*512);
        cbh1 = *(const bfrag8*)(b1p + (ks+1)*512);
        cbl1 = *(const bfrag8*)(b1lp + (ks+1)*512);
      }
      #pragma unroll
      for(int mt=0;mt<2;mt++){
        bfrag8 ah = *(const bfrag8*)(SH + (mt*16+r16)*168 + g*8 + ks*32);
        bfrag8 al = *(const bfrag8*)(SL + (mt*16+r16)*168 + g*8 + ks*32);
        acc[0][mt]=MFMA(ah,bh0,acc[0][mt]); acc[0][mt]=MFMA(ah,bl0,acc[0][mt]); acc[0][mt]=MFMA(al,bh0,acc[0][mt]);
        acc[1][mt]=MFMA(ah,bh1,acc[1][mt]); acc[1][mt]=MFMA(ah,bl1,acc[1][mt]); acc[1][mt]=MFMA(al,bh1,acc[1][mt]);
      }
    }
    __syncthreads();   // all waves done reading X
    #pragma unroll
    for(int u=0;u<2;u++){
      int c = (w+u*4)*16 + r16;
      float bv = b1[c];
      #pragma unroll
      for(int mt=0;mt<2;mt++)
        #pragma unroll
        for(int r=0;r<4;r++){
          float v = fmaxf(acc[u][mt][r] + bv, 0.f);
          int row = mt*16 + g*4 + r;
          u16 h = f2bf(v);
          SH[row*136+c] = h; SL[row*136+c] = f2bf(v - bf2f(h));
        }
    }
  }
  __syncthreads();

  // ---- layer 2: K=128 (4 ks), N=128; regs across barrier, overwrite A ----
  {
    f32x4 acc[2][2];
    #pragma unroll
    for(int u=0;u<2;u++)
      #pragma unroll
      for(int mt=0;mt<2;mt++) acc[u][mt] = (f32x4){0.f,0.f,0.f,0.f};
    const u16* b0h = P2h + ((size_t)(w*4))*512 + lane*8;
    const u16* b0l = P2l + ((size_t)(w*4))*512 + lane*8;
    const u16* b1p = P2h + ((size_t)((w+4)*4))*512 + lane*8;
    const u16* b1lp= P2l + ((size_t)((w+4)*4))*512 + lane*8;
    bfrag8 cbh0 = *(const bfrag8*)(b0h);
    bfrag8 cbl0 = *(const bfrag8*)(b0l);
    bfrag8 cbh1 = *(const bfrag8*)(b1p);
    bfrag8 cbl1 = *(const bfrag8*)(b1lp);
    #pragma unroll
    for(int ks=0;ks<4;ks++){
      bfrag8 bh0=cbh0, bl0=cbl0, bh1=cbh1, bl1=cbl1;
      if(ks<3){
        cbh0 = *(const bfrag8*)(b0h + (ks+1)*512);
        cbl0 = *(const bfrag8*)(b0l + (ks+1)*512);
        cbh1 = *(const bfrag8*)(b1p + (ks+1)*512);
        cbl1 = *(const bfrag8*)(b1lp + (ks+1)*512);
      }
      #pragma unroll
      for(int mt=0;mt<2;mt++){
        bfrag8 ah = *(const bfrag8*)(SH + (mt*16+r16)*136 + g*8 + ks*32);
        bfrag8 al = *(const bfrag8*)(SL + (mt*16+r16)*136 + g*8 + ks*32);
        acc[0][mt]=MFMA(ah,bh0,acc[0][mt]); acc[0][mt]=MFMA(ah,bl0,acc[0][mt]); acc[0][mt]=MFMA(al,bh0,acc[0][mt]);
        acc[1][mt]=MFMA(ah,bh1,acc[1][mt]); acc[1][mt]=MFMA(ah,bl1,acc[1][mt]); acc[1][mt]=MFMA(al,bh1,acc[1][mt]);
      }
    }
    __syncthreads();   // all waves done reading A(layer1)
    #pragma unroll
    for(int u=0;u<2;u++){
      int c = (w+u*4)*16 + r16;
      float bv = b2[c];
      #pragma unroll
      for(int mt=0;mt<2;mt++)
        #pragma unroll
        for(int r=0;r<4;r++){
          float v = fmaxf(acc[u][mt][r] + bv, 0.f);
          int row = mt*16 + g*4 + r;
          u16 h = f2bf(v);
          SH[row*136+c] = h; SL[row*136+c] = f2bf(v - bf2f(h));
        }
    }
  }
  __syncthreads();

  // ---- layer 3: K=128, 20 subtiles over 4 waves (5 chains/wave), flattened prefetch ----
  {
    f32x4 acc[5];
    #pragma unroll
    for(int s=0;s<5;s++) acc[s] = (f32x4){0.f,0.f,0.f,0.f};
    // flattened iteration space: idx2 = s*4 + ks, subtile idx = w*5+s, nt = idx>>1, mt = idx&1
    const u16* base3h = P3h + (size_t)lane*8;
    const u16* base3l = P3l + (size_t)lane*8;
    int nt0 = (w*5)>>1;
    bfrag8 cbh = *(const bfrag8*)(base3h + (size_t)(nt0*4)*512);
    bfrag8 cbl = *(const bfrag8*)(base3l + (size_t)(nt0*4)*512);
    #pragma unroll
    for(int s=0;s<5;s++){
      int idx = w*5 + s, nt = idx>>1, mt = idx&1;
      #pragma unroll
      for(int ks=0;ks<4;ks++){
        bfrag8 bh=cbh, bl=cbl;
        if(!(s==4 && ks==3)){
          int ns = s + ((ks==3)?1:0);
          int nks = (ks==3)?0:(ks+1);
          int nidx = w*5 + ns, nnt = nidx>>1;
          cbh = *(const bfrag8*)(base3h + (size_t)(nnt*4+nks)*512);
          cbl = *(const bfrag8*)(base3l + (size_t)(nnt*4+nks)*512);
        }
        bfrag8 ah = *(const bfrag8*)(SH + (mt*16+r16)*136 + g*8 + ks*32);
        bfrag8 al = *(const bfrag8*)(SL + (mt*16+r16)*136 + g*8 + ks*32);
        acc[s]=MFMA(ah,bh,acc[s]); acc[s]=MFMA(ah,bl,acc[s]); acc[s]=MFMA(al,bh,acc[s]);
      }
    }
    #pragma unroll
    for(int s=0;s<5;s++){
      int idx = w*5 + s, nt = idx>>1, mt = idx&1;
      int c = nt*16 + r16;
      if(c < 156){
        float bv = b3[c];
        #pragma unroll
        for(int r=0;r<4;r++){
          int p = mt*16 + g*4 + r;
          float v = acc[s][r] + bv;
          float e = expf(v);
          float y = Y[(p0+p)*NB + c];
          int cls = cis[p];
          atomicAdd(&csum[cls*160 + c], e);
          atomicAdd(&cwsum[cls*160 + c], e*y);
        }
      }
    }
  }
  __syncthreads();
  float* gs = gsum  + (size_t)(blockIdx.x & 255)*480;
  float* gw = gwsum + (size_t)(blockIdx.x & 255)*480;
  for(int i=t;i<480;i+=256){
    atomicAdd(&gs[i], csum[i]);
    atomicAdd(&gw[i], cwsum[i]);
  }
}

__global__ void k_finalM(const float* __restrict__ gsump, const float* __restrict__ gwsump, float* __restrict__ M){
  int e = blockIdx.x*256 + threadIdx.x;
  if(e < 468){
    int cls = e/156, c = e - cls*156;
    float s=0.f, wv=0.f;
    for(int k=0;k<256;k++){ s += gsump[(size_t)k*480 + cls*160 + c]; wv += gwsump[(size_t)k*480 + cls*160 + c]; }
    M[e] = (s > 0.f) ? (wv / fmaxf(s, 1e-30f)) : 0.f;
  }
}

// ---------- Y_hat = S_flat @ M, float4 stores ----------
__global__ void k_yhat4(const float* __restrict__ Sf, const float* __restrict__ M, float4* __restrict__ out){
  unsigned idx = blockIdx.x*256u + threadIdx.x;   // N_PIX*39 float4s, grid exact
  unsigned p = idx / 39u, q = idx - p*39u;
  unsigned c0 = q*4u;
  float4 m0 = *(const float4*)(M + c0);
  float4 m1 = *(const float4*)(M + 156 + c0);
  float4 m2 = *(const float4*)(M + 312 + c0);
  float s0 = Sf[(size_t)p*3+0], s1 = Sf[(size_t)p*3+1], s2 = Sf[(size_t)p*3+2];
  float4 r;
  r.x = s0*m0.x + s1*m1.x + s2*m2.x;
  r.y = s0*m0.y + s1*m1.y + s2*m2.y;
  r.z = s0*m0.z + s1*m1.z + s2*m2.z;
  r.w = s0*m0.w + s1*m1.w + s2*m2.w;
  out[idx] = r;
}

extern "C" void kernel_launch(void* const* d_in, const int* in_sizes, int n_in,
                              void* d_out, int out_size, void* d_ws, size_t ws_size,
                              hipStream_t stream){
  const float* Y    = (const float*)d_in[0];
  const int*   seg0 = (const int*)d_in[1];
  const int*   A0   = (const int*)d_in[2];
  const int*   seg1 = (const int*)d_in[3];
  const int*   A1   = (const int*)d_in[4];
  const int*   seg2 = (const int*)d_in[5];
  const int*   A2   = (const int*)d_in[6];
  const float* attn = (const float*)d_in[7];
  const float* alpha= (const float*)d_in[8];
  const float* sw   = (const float*)d_in[9];
  const float* W1a[3] = {(const float*)d_in[10], (const float*)d_in[14], (const float*)d_in[18]};
  const float* b1a[3] = {(const float*)d_in[11], (const float*)d_in[15], (const float*)d_in[19]};
  const float* W2a[3] = {(const float*)d_in[12], (const float*)d_in[16], (const float*)d_in[20]};
  const float* b2a[3] = {(const float*)d_in[13], (const float*)d_in[17], (const float*)d_in[21]};
  const float* Wm1=(const float*)d_in[22]; const float* bm1=(const float*)d_in[23];
  const float* Wm2=(const float*)d_in[24]; const float* bm2=(const float*)d_in[25];
  const float* Wm3=(const float*)d_in[26]; const float* bm3=(const float*)d_in[27];
  float* out = (float*)d_out;

  const int nseg[3] = {2000, 1000, 500};
  const int* Aarr[3]   = {A0, A1, A2};

  char* base = (char*)d_ws;
  size_t off = 0;
  auto alloc = [&](size_t bytes)->char*{
    char* r = base + off;
    off += (bytes + 255) & ~(size_t)255;
    return r;
  };
  int* cnt[3]; int* offs[3]; int* cur[3]; int* lst[3]; float* X[3]; float* Ss[3];
  for(int i=0;i<3;i++) cnt[i]  = (int*)alloc((size_t)nseg[i]*4);
  for(int i=0;i<3;i++) offs[i] = (int*)alloc((size_t)nseg[i]*4);
  for(int i=0;i<3;i++) cur[i]  = (int*)alloc((size_t)nseg[i]*4);
  for(int i=0;i<3;i++) lst[i]  = (int*)alloc((size_t)N_PIX*4);
  for(int i=0;i<3;i++) X[i]    = (float*)alloc((size_t)nseg[i]*NB*4);
  float* Hn   = (float*)alloc((size_t)2000*64*4);
  float* x1b  = (float*)alloc((size_t)2000*64*4);
  float* Hn2  = (float*)alloc((size_t)2000*3*4);
  for(int i=0;i<3;i++) Ss[i]   = (float*)alloc((size_t)nseg[i]*3*4);
  float* cst   = (float*)alloc(64);
  float* fused = (float*)alloc((size_t)N_PIX*3*4);
  float* spsum = (float*)alloc((size_t)2000*3*4);
  float* smth  = (float*)alloc((size_t)2000*3*4);
  float* Sf    = (float*)alloc((size_t)N_PIX*3*4);
  int*   ci    = (int*)alloc((size_t)N_PIX*4);
  u16* P1h = (u16*)alloc((size_t)20480*2); u16* P1l = (u16*)alloc((size_t)20480*2);
  u16* P2h = (u16*)alloc((size_t)16384*2); u16* P2l = (u16*)alloc((size_t)16384*2);
  u16* P3h = (u16*)alloc((size_t)20480*2); u16* P3l = (u16*)alloc((size_t)20480*2);
  float* gsump  = (float*)alloc((size_t)256*480*4);
  float* gwsump = (float*)alloc((size_t)256*480*4);
  float* Mbuf   = (float*)alloc((size_t)480*4);

  // per-call re-init of all accumulators (replay/poison safe)
  for(int i=0;i<3;i++) hipMemsetAsync(cnt[i], 0, (size_t)nseg[i]*4, stream);
  hipMemsetAsync(spsum, 0, (size_t)2000*3*4, stream);
  hipMemsetAsync(gsump, 0, (size_t)256*480*4, stream);
  hipMemsetAsync(gwsump, 0, (size_t)256*480*4, stream);
  k_prep<<<1,64,0,stream>>>(sw, alpha, cst);

  // weight pre-pack (independent of everything else)
  k_packw<<<(8*5*512+255)/256,256,0,stream>>>(Wm1, 156, 128, 5, 8, P1h, P1l);
  k_packw<<<(8*4*512+255)/256,256,0,stream>>>(Wm2, 128, 128, 4, 8, P2h, P2l);
  k_packw<<<(10*4*512+255)/256,256,0,stream>>>(Wm3, 128, 156, 4, 10, P3h, P3l);

  // CSR + segment means (all 3 scales fused)
  k_count<<<N_PIX/256,256,0,stream>>>(seg0,seg1,seg2,cnt[0],cnt[1],cnt[2]);
  k_scan<<<3,256,0,stream>>>(cnt[0],cnt[1],cnt[2],offs[0],offs[1],offs[2],cur[0],cur[1],cur[2]);
  k_fill<<<N_PIX/256,256,0,stream>>>(seg0,seg1,seg2,cur[0],cur[1],cur[2],lst[0],lst[1],lst[2]);
  k_segmean3<<<3500,128,0,stream>>>(Y,
      offs[0],cnt[0],lst[0],X[0],
      offs[1],cnt[1],lst[1],X[1],
      offs[2],cnt[2],lst[2],X[2]);

  // Multi-scale GAT encoder
  for(int i=0;i<3;i++){
    int n = nseg[i];
    k_linear<<<(n*64+255)/256,256,0,stream>>>(X[i],  W1a[i], b1a[i], Hn,  n, NB, 64);
    k_attn4<64,false><<<n/4,256,0,stream>>>(Hn, Aarr[i], x1b, n);
    k_linear<<<(n*3+255)/256,256,0,stream>>>(x1b, W2a[i], b2a[i], Hn2, n, 64, 3);
    k_attn4<3,true><<<n/4,256,0,stream>>>(Hn2, Aarr[i], Ss[i], n);
  }

  // fuse + PCR
  k_fuse<<<N_PIX/256,256,0,stream>>>(seg0,seg1,seg2,Ss[0],Ss[1],Ss[2],cst,fused,spsum);
  k_pcr<<<2000,256,0,stream>>>(attn, spsum, cnt[0], smth);
  k_sflat<<<N_PIX/256,256,0,stream>>>(fused, seg0, smth, cst, Sf, ci);

  // ACDE: single-pass MFMA MLP + per-class exp sums
  k_mlp_mfma<<<N_PIX/32,256,0,stream>>>(Y, ci, P1h,P1l,P2h,P2l,P3h,P3l, bm1,bm2,bm3, gsump, gwsump);
  k_finalM<<<2,256,0,stream>>>(gsump, gwsump, Mbuf);
  k_yhat4<<<(N_PIX/256)*39,256,0,stream>>>(Sf, Mbuf, (float4*)out);
  (void)in_sizes; (void)n_in; (void)out_size;
}